// Round 13
// baseline (138.476 us; speedup 1.0000x reference)
//
#include <hip/hip_runtime.h>
#include <hip/hip_bf16.h>

typedef __attribute__((ext_vector_type(4)))  float f32x4;
typedef __attribute__((ext_vector_type(16))) float f32x16;
typedef __attribute__((ext_vector_type(8)))  short short8;
typedef __attribute__((ext_vector_type(4)))  short short4v;

__device__ __forceinline__ short f2bf(float f) {
  union { float f; unsigned u; } x; x.f = f;
  unsigned r = (x.u + 0x7FFFu + ((x.u >> 16) & 1u)) >> 16;
  return (short)r;
}
__device__ __forceinline__ float bf2f(short s) {
  union { unsigned u; float f; } x; x.u = ((unsigned)(unsigned short)s) << 16;
  return x.f;
}
__device__ __forceinline__ unsigned cvtpk(float lo, float hi) {
  unsigned r;
  asm("v_cvt_pk_bf16_f32 %0, %1, %2" : "=v"(r) : "v"(lo), "v"(hi));
  return r;
}

// ---------------- cast f32 -> bf16, vectorized x4 ----------------
__global__ __launch_bounds__(256) void k_cast(const float* __restrict__ in,
                                              short* __restrict__ out, int n4) {
  int i = blockIdx.x * 256 + threadIdx.x;
  if (i >= n4) return;
  f32x4 v = ((const f32x4*)in)[i];
  short4v s;
  s[0] = f2bf(v[0]); s[1] = f2bf(v[1]); s[2] = f2bf(v[2]); s[3] = f2bf(v[3]);
  ((short4v*)out)[i] = s;
}

// ---------------- pack w_q/w_k/w_v -> WqkvT bf16 [3072][1024] ----------------
__global__ __launch_bounds__(256) void k_pack(const float* __restrict__ wq,
                                              const float* __restrict__ wk,
                                              const float* __restrict__ wv,
                                              short* __restrict__ WT) {
  int nt = blockIdx.x, et = blockIdx.y, sel = blockIdx.z;
  const float* w = sel == 0 ? wq : (sel == 1 ? wk : wv);
  __shared__ float tile[64][65];
  int tid = threadIdx.x;
  int cl = tid & 63, rw = tid >> 6;
#pragma unroll
  for (int j = 0; j < 16; ++j) {
    int el = j * 4 + rw;
    tile[el][cl] = w[(size_t)(et * 64 + el) * 1024 + nt * 64 + cl];
  }
  __syncthreads();
#pragma unroll
  for (int j = 0; j < 16; ++j) {
    int nl = j * 4 + rw;
    int n = sel * 1024 + nt * 64 + nl;
    WT[(size_t)n * 1024 + et * 64 + cl] = f2bf(tile[cl][nl]);
  }
}

// ---------------- GEMM C[M][N] = A[M][K] * B^T[N][K], bf16 in, f32 acc ----------------
// Reg-staged prefetch (verified-fastest config for this problem size).
// EPI==0: scatter Q(*0.125*log2e)/K -> [BH][2048][64], V -> V^T [BH][64][2048]; EPI==1: f32 out
template <int EPI>
__global__ __launch_bounds__(256) void k_gemm(const short* __restrict__ A,
                                              const short* __restrict__ B,
                                              short* __restrict__ Qo, short* __restrict__ Ko,
                                              short* __restrict__ Vo, float* __restrict__ out,
                                              int M, int N, int K) {
  __shared__ short As[128][40];
  __shared__ short Bs[128][40];
  int tid = threadIdx.x;
  int bm = blockIdx.y * 128, bn = blockIdx.x * 128;
  int wid = tid >> 6, lane = tid & 63;
  int wm = (wid >> 1) * 64, wn = (wid & 1) * 64;
  int lg = lane >> 4, lr = lane & 15;
  f32x4 acc[4][4] = {};

  int sr = tid >> 2, sc = tid & 3;
  const short* Ar0 = A + (size_t)(bm + sr) * K;
  const short* Ar1 = A + (size_t)(bm + sr + 64) * K;
  const short* Br0 = B + (size_t)(bn + sr) * K;
  const short* Br1 = B + (size_t)(bn + sr + 64) * K;

  short8 pa0 = *(const short8*)&Ar0[sc * 8];
  short8 pa1 = *(const short8*)&Ar1[sc * 8];
  short8 pb0 = *(const short8*)&Br0[sc * 8];
  short8 pb1 = *(const short8*)&Br1[sc * 8];

  int nk = K >> 5;
  for (int kt = 0; kt < nk; ++kt) {
    __syncthreads();
    *(short8*)&As[sr][sc * 8] = pa0;
    *(short8*)&As[sr + 64][sc * 8] = pa1;
    *(short8*)&Bs[sr][sc * 8] = pb0;
    *(short8*)&Bs[sr + 64][sc * 8] = pb1;
    if (kt + 1 < nk) {
      int ko = (kt + 1) * 32;
      pa0 = *(const short8*)&Ar0[ko + sc * 8];
      pa1 = *(const short8*)&Ar1[ko + sc * 8];
      pb0 = *(const short8*)&Br0[ko + sc * 8];
      pb1 = *(const short8*)&Br1[ko + sc * 8];
    }
    __syncthreads();
    short8 af[4], bf_[4];
#pragma unroll
    for (int mt = 0; mt < 4; ++mt)
      af[mt] = *(const short8*)&As[wm + mt * 16 + lr][lg * 8];
#pragma unroll
    for (int ntl = 0; ntl < 4; ++ntl)
      bf_[ntl] = *(const short8*)&Bs[wn + ntl * 16 + lr][lg * 8];
#pragma unroll
    for (int mt = 0; mt < 4; ++mt)
#pragma unroll
      for (int ntl = 0; ntl < 4; ++ntl)
        acc[mt][ntl] = __builtin_amdgcn_mfma_f32_16x16x32_bf16(af[mt], bf_[ntl], acc[mt][ntl], 0, 0, 0);
  }

#pragma unroll
  for (int mt = 0; mt < 4; ++mt)
#pragma unroll
    for (int ntl = 0; ntl < 4; ++ntl)
#pragma unroll
      for (int rr = 0; rr < 4; ++rr) {
        int m = bm + wm + mt * 16 + lg * 4 + rr;
        int n = bn + wn + ntl * 16 + lr;
        float val = acc[mt][ntl][rr];
        if (EPI == 0) {
          int b = m >> 11, s = m & 2047;
          int sel = n >> 10, hk = n & 1023;
          int h = hk >> 6, kd = hk & 63;
          // 0.125 * log2(e): logits in log2 domain -> exp2 in softmax
          if (sel == 0) Qo[((size_t)(b * 16 + h) * 2048 + s) * 64 + kd] = f2bf(val * 0.18033688011112042f);
          else if (sel == 1) Ko[((size_t)(b * 16 + h) * 2048 + s) * 64 + kd] = f2bf(val);
          else Vo[((size_t)(b * 16 + h) * 64 + kd) * 2048 + s] = f2bf(val);  // V^T
        } else {
          out[(size_t)m * 1024 + n] = val;
        }
      }
}

// ---------------- causal flash attention: no-max softmax + 2-way kv-split ----------------
// Q,K: [32][2048][64] bf16 (Q pre-scaled 1/8*log2e). VT: [32][64][2048].
// Block = 2 waves = (qw=2g, half) and (qw=2g+1, half): both halves' tile ranges coincide
// ([0,g+1) for h=0, [g+1,2g+2) for h=1) so LDS staging stays shared. Grid 32x64 ->
// 16 waves/CU static. No-max partials are same-scale, so merge is a pure add.
// Partials: P0/P1 [32*2048][64] bf16 (unnormalized O), ML [32*2048][2] f32 (l per half).
__global__ __launch_bounds__(128, 4) void k_attn(const short* __restrict__ Q,
                                                 const short* __restrict__ K,
                                                 const short* __restrict__ VT,
                                                 short* __restrict__ P0,
                                                 short* __restrict__ P1,
                                                 float* __restrict__ ML) {
  const int S = 2048;
  int bh = blockIdx.x;
  int y = blockIdx.y;
  int h = y & 1;
  int g = 31 - (y >> 1);  // LPT: largest tile-count blocks dispatch first

  int tid = threadIdx.x;
  int wid = tid >> 6, lane = tid & 63;
  int hi = lane >> 5, ln = lane & 31;
  int qw = 2 * g + wid;
  int q_g = qw * 32 + ln;
  int tb = h * (g + 1);      // first staged tile
  int nstage = g + 1;        // tiles staged by this block
  int te_w = qw + 1;         // wave active while t < te_w

  __shared__ short Ks[2][32][64];
  __shared__ short Vs[2][64][32];

  const short* Qb = Q + (size_t)bh * S * 64;
  const short* Kb = K + (size_t)bh * S * 64;
  const short* Vb = VT + (size_t)bh * 64 * S;

  // Q fragments: B[k=d][col=q]
  short8 qf[4];
#pragma unroll
  for (int ds = 0; ds < 4; ++ds)
    qf[ds] = *(const short8*)&Qb[(size_t)q_g * 64 + ds * 16 + hi * 8];

  // staging thread mapping (shared across both waves)
  int kr = tid >> 2, kcb = tid & 3;          // K: row 0..31, chunks kcb, kcb+4
  int vd = tid >> 1, vcb = tid & 1;          // V: row d 0..63, chunks vcb, vcb+2
  const short* kgp = Kb + (size_t)kr * 64;
  const short* vgp = Vb + (size_t)vd * S;

  // prefetch first tile of this block's range
  size_t ko0 = (size_t)tb * 2048;
  size_t vo0 = (size_t)tb * 32;
  short8 kreg0 = *(const short8*)&kgp[ko0 + kcb * 8];
  short8 kreg1 = *(const short8*)&kgp[ko0 + (kcb + 4) * 8];
  short8 vreg0 = *(const short8*)&vgp[vo0 + vcb * 8];
  short8 vreg1 = *(const short8*)&vgp[vo0 + (vcb + 2) * 8];

  f32x16 acoA = {}, acoB = {};
  float l = 0.f;  // per-lane partial; merged across the lane^32 pair at the end

  for (int i = 0; i < nstage; ++i) {
    int t = tb + i;
    int buf = i & 1;
    // stage current tile (swizzled)
    *(short8*)&Ks[buf][kr][(kcb ^ (kr & 7)) * 8]       = kreg0;
    *(short8*)&Ks[buf][kr][((kcb + 4) ^ (kr & 7)) * 8] = kreg1;
    *(short8*)&Vs[buf][vd][(vcb ^ (vd & 3)) * 8]       = vreg0;
    *(short8*)&Vs[buf][vd][((vcb + 2) ^ (vd & 3)) * 8] = vreg1;
    // prefetch next tile (latency hides under compute)
    if (i + 1 < nstage) {
      size_t ko = (size_t)(t + 1) * 2048;
      size_t vo = (size_t)(t + 1) * 32;
      kreg0 = *(const short8*)&kgp[ko + kcb * 8];
      kreg1 = *(const short8*)&kgp[ko + (kcb + 4) * 8];
      vreg0 = *(const short8*)&vgp[vo + vcb * 8];
      vreg1 = *(const short8*)&vgp[vo + (vcb + 2) * 8];
    }
    __syncthreads();

    if (t < te_w) {
      // K fragments from LDS: A[row=kv][k=d]
      short8 kc0 = *(const short8*)&Ks[buf][ln][((0 + hi) ^ (ln & 7)) * 8];
      short8 kc1 = *(const short8*)&Ks[buf][ln][((2 + hi) ^ (ln & 7)) * 8];
      short8 kc2 = *(const short8*)&Ks[buf][ln][((4 + hi) ^ (ln & 7)) * 8];
      short8 kc3 = *(const short8*)&Ks[buf][ln][((6 + hi) ^ (ln & 7)) * 8];
      // S[kv][q] = K Q^T (log2 domain)
      f32x16 sa = {};
      __builtin_amdgcn_s_setprio(1);
      sa = __builtin_amdgcn_mfma_f32_32x32x16_bf16(kc0, qf[0], sa, 0, 0, 0);
      sa = __builtin_amdgcn_mfma_f32_32x32x16_bf16(kc1, qf[1], sa, 0, 0, 0);
      sa = __builtin_amdgcn_mfma_f32_32x32x16_bf16(kc2, qf[2], sa, 0, 0, 0);
      sa = __builtin_amdgcn_mfma_f32_32x32x16_bf16(kc3, qf[3], sa, 0, 0, 0);
      __builtin_amdgcn_s_setprio(0);

      if (t == qw) {  // diagonal tile: causal mask
#pragma unroll
        for (int r = 0; r < 16; ++r) {
          int kv_g = t * 32 + (r & 3) + 8 * (r >> 2) + 4 * hi;
          if (kv_g > q_g) sa[r] = -1e30f;
        }
      }

      // V^T fragments from LDS: A[row=d][k=kv]
      short8 v00 = *(const short8*)&Vs[buf][ln][((0 + hi) ^ (ln & 3)) * 8];
      short8 v01 = *(const short8*)&Vs[buf][ln][((2 + hi) ^ (ln & 3)) * 8];
      short8 v10 = *(const short8*)&Vs[buf][32 + ln][((0 + hi) ^ (ln & 3)) * 8];
      short8 v11 = *(const short8*)&Vs[buf][32 + ln][((2 + hi) ^ (ln & 3)) * 8];

      // no-max softmax: p = exp2(sa) directly (bounded logits; f32 headroom analyzed)
      float p[16];
#pragma unroll
      for (int r = 0; r < 16; ++r) p[r] = exp2f(sa[r]);
      float s0 = (p[0] + p[1]) + (p[2] + p[3]);
      float s1 = (p[4] + p[5]) + (p[6] + p[7]);
      float s2 = (p[8] + p[9]) + (p[10] + p[11]);
      float s3 = (p[12] + p[13]) + (p[14] + p[15]);
      l += (s0 + s1) + (s2 + s3);

      // assemble P^T fragments (B[k=kv][col=q]) via cvt_pk + lane^32 exchange
#pragma unroll
      for (int s = 0; s < 2; ++s) {
        unsigned c0 = cvtpk(p[8 * s + 0], p[8 * s + 1]);
        unsigned c1 = cvtpk(p[8 * s + 2], p[8 * s + 3]);
        unsigned c2 = cvtpk(p[8 * s + 4], p[8 * s + 5]);
        unsigned c3 = cvtpk(p[8 * s + 6], p[8 * s + 7]);
        unsigned pc0 = (unsigned)__shfl_xor((int)c0, 32);
        unsigned pc1 = (unsigned)__shfl_xor((int)c1, 32);
        unsigned pc2 = (unsigned)__shfl_xor((int)c2, 32);
        unsigned pc3 = (unsigned)__shfl_xor((int)c3, 32);
        union { unsigned u[4]; short8 v; } pb;
        pb.u[0] = hi ? pc2 : c0;
        pb.u[1] = hi ? pc3 : c1;
        pb.u[2] = hi ? c2 : pc0;
        pb.u[3] = hi ? c3 : pc1;
        __builtin_amdgcn_s_setprio(1);
        if (s == 0) {
          acoA = __builtin_amdgcn_mfma_f32_32x32x16_bf16(v00, pb.v, acoA, 0, 0, 0);
          acoB = __builtin_amdgcn_mfma_f32_32x32x16_bf16(v10, pb.v, acoB, 0, 0, 0);
        } else {
          acoA = __builtin_amdgcn_mfma_f32_32x32x16_bf16(v01, pb.v, acoA, 0, 0, 0);
          acoB = __builtin_amdgcn_mfma_f32_32x32x16_bf16(v11, pb.v, acoB, 0, 0, 0);
        }
        __builtin_amdgcn_s_setprio(0);
      }
    }
  }

  // merge the lane^32 pair's l, write unnormalized partial + l
  l += __shfl_xor(l, 32);
  int row = (bh << 11) + q_g;
  ML[row * 2 + h] = l;
  short* Op = h ? P1 : P0;
  size_t base = (size_t)row * 64;
#pragma unroll
  for (int g4 = 0; g4 < 4; ++g4) {
    int d0 = 8 * g4 + 4 * hi;
    *(unsigned*)&Op[base + d0]          = cvtpk(acoA[4 * g4], acoA[4 * g4 + 1]);
    *(unsigned*)&Op[base + d0 + 2]      = cvtpk(acoA[4 * g4 + 2], acoA[4 * g4 + 3]);
    *(unsigned*)&Op[base + 32 + d0]     = cvtpk(acoB[4 * g4], acoB[4 * g4 + 1]);
    *(unsigned*)&Op[base + 32 + d0 + 2] = cvtpk(acoB[4 * g4 + 2], acoB[4 * g4 + 3]);
  }
}

// ---------------- merge halves: O = (P0 + P1) / (l0 + l1) -> Ob [2][2048][1024] bf16 ----------
__global__ __launch_bounds__(256) void k_merge(const short* __restrict__ P0,
                                               const short* __restrict__ P1,
                                               const float* __restrict__ ML,
                                               short* __restrict__ O) {
  int gi = blockIdx.x * 256 + threadIdx.x;  // 262144
  int row = gi >> 2;                        // bh*2048 + q
  int dc = (gi & 3) << 4;
  float w = 1.f / (ML[row * 2] + ML[row * 2 + 1]);
  size_t pbase = (size_t)row * 64 + dc;
  short8 a0 = *(const short8*)&P0[pbase];
  short8 a1 = *(const short8*)&P0[pbase + 8];
  short8 b0 = *(const short8*)&P1[pbase];
  short8 b1 = *(const short8*)&P1[pbase + 8];
  int bh = row >> 11, q = row & 2047;
  int b = bh >> 4, h = bh & 15;
  size_t obase = ((size_t)b * 2048 + q) * 1024 + h * 64 + dc;
  short8 o0, o1;
#pragma unroll
  for (int j = 0; j < 8; ++j) {
    o0[j] = f2bf((bf2f(a0[j]) + bf2f(b0[j])) * w);
    o1[j] = f2bf((bf2f(a1[j]) + bf2f(b1[j])) * w);
  }
  *(short8*)&O[obase] = o0;
  *(short8*)&O[obase + 8] = o1;
}

extern "C" void kernel_launch(void* const* d_in, const int* in_sizes, int n_in,
                              void* d_out, int out_size, void* d_ws, size_t ws_size,
                              hipStream_t stream) {
  const float* x  = (const float*)d_in[0];
  const float* wq = (const float*)d_in[1];
  const float* wk = (const float*)d_in[2];
  const float* wv = (const float*)d_in[3];
  const float* wo = (const float*)d_in[4];
  float* out = (float*)d_out;
  char* ws = (char*)d_ws;

  short* x_bf  = (short*)(ws);                       // 8 MB (dead after gemm0)
  short* WqkvT = (short*)(ws + ((size_t)8 << 20));   // 6 MB (dead after gemm0)
  short* wo_bf = (short*)(ws + ((size_t)14 << 20));  // 2 MB
  short* Qb    = (short*)(ws + ((size_t)16 << 20));  // 8 MB
  short* Kb    = (short*)(ws + ((size_t)24 << 20));  // 8 MB
  short* Vt    = (short*)(ws + ((size_t)32 << 20));  // 8 MB (V^T)
  short* Ob    = (short*)(ws + ((size_t)40 << 20));  // 8 MB
  short* P0    = (short*)(ws);                       // 8 MB, overlays x_bf
  float* ML    = (float*)(ws + ((size_t)8 << 20));   // 512 KB, overlays WqkvT
  short* P1    = (short*)(ws + ((size_t)48 << 20));  // 8 MB

  k_cast<<<4096, 256, 0, stream>>>(x, x_bf, 1048576);
  k_cast<<<1024, 256, 0, stream>>>(wo, wo_bf, 262144);
  k_pack<<<dim3(16, 16, 3), 256, 0, stream>>>(wq, wk, wv, WqkvT);
  k_gemm<0><<<dim3(24, 32), 256, 0, stream>>>(x_bf, WqkvT, Qb, Kb, Vt, nullptr, 4096, 3072, 1024);
  k_attn<<<dim3(32, 64), 128, 0, stream>>>(Qb, Kb, Vt, P0, P1, ML);
  k_merge<<<1024, 256, 0, stream>>>(P0, P1, ML, Ob);
  k_gemm<1><<<dim3(8, 32), 256, 0, stream>>>(Ob, wo_bf, nullptr, nullptr, nullptr, out, 4096, 1024, 1024);
}

// Round 14
// 129.719 us; speedup vs baseline: 1.0675x; 1.0675x over previous
//
#include <hip/hip_runtime.h>
#include <hip/hip_bf16.h>

typedef __attribute__((ext_vector_type(4)))  float f32x4;
typedef __attribute__((ext_vector_type(16))) float f32x16;
typedef __attribute__((ext_vector_type(8)))  short short8;
typedef __attribute__((ext_vector_type(4)))  short short4v;

__device__ __forceinline__ short f2bf(float f) {
  union { float f; unsigned u; } x; x.f = f;
  unsigned r = (x.u + 0x7FFFu + ((x.u >> 16) & 1u)) >> 16;
  return (short)r;
}
__device__ __forceinline__ unsigned cvtpk(float lo, float hi) {
  unsigned r;
  asm("v_cvt_pk_bf16_f32 %0, %1, %2" : "=v"(r) : "v"(lo), "v"(hi));
  return r;
}

// ---------------- cast f32 -> bf16, vectorized x4 ----------------
__global__ __launch_bounds__(256) void k_cast(const float* __restrict__ in,
                                              short* __restrict__ out, int n4) {
  int i = blockIdx.x * 256 + threadIdx.x;
  if (i >= n4) return;
  f32x4 v = ((const f32x4*)in)[i];
  short4v s;
  s[0] = f2bf(v[0]); s[1] = f2bf(v[1]); s[2] = f2bf(v[2]); s[3] = f2bf(v[3]);
  ((short4v*)out)[i] = s;
}

// ---------------- pack w_q/w_k/w_v -> WqkvT bf16 [3072][1024] ----------------
__global__ __launch_bounds__(256) void k_pack(const float* __restrict__ wq,
                                              const float* __restrict__ wk,
                                              const float* __restrict__ wv,
                                              short* __restrict__ WT) {
  int nt = blockIdx.x, et = blockIdx.y, sel = blockIdx.z;
  const float* w = sel == 0 ? wq : (sel == 1 ? wk : wv);
  __shared__ float tile[64][65];
  int tid = threadIdx.x;
  int cl = tid & 63, rw = tid >> 6;
#pragma unroll
  for (int j = 0; j < 16; ++j) {
    int el = j * 4 + rw;
    tile[el][cl] = w[(size_t)(et * 64 + el) * 1024 + nt * 64 + cl];
  }
  __syncthreads();
#pragma unroll
  for (int j = 0; j < 16; ++j) {
    int nl = j * 4 + rw;
    int n = sel * 1024 + nt * 64 + nl;
    WT[(size_t)n * 1024 + et * 64 + cl] = f2bf(tile[cl][nl]);
  }
}

// ---------------- GEMM C[M][N] = A[M][K] * B^T[N][K], bf16 in, f32 acc ----------------
// Reg-staged prefetch (verified-fastest config for this problem size).
// EPI==0: scatter Q(*0.125*log2e)/K -> [BH][2048][64], V -> V^T [BH][64][2048]; EPI==1: f32 out
template <int EPI>
__global__ __launch_bounds__(256) void k_gemm(const short* __restrict__ A,
                                              const short* __restrict__ B,
                                              short* __restrict__ Qo, short* __restrict__ Ko,
                                              short* __restrict__ Vo, float* __restrict__ out,
                                              int M, int N, int K) {
  __shared__ short As[128][40];
  __shared__ short Bs[128][40];
  int tid = threadIdx.x;
  int bm = blockIdx.y * 128, bn = blockIdx.x * 128;
  int wid = tid >> 6, lane = tid & 63;
  int wm = (wid >> 1) * 64, wn = (wid & 1) * 64;
  int lg = lane >> 4, lr = lane & 15;
  f32x4 acc[4][4] = {};

  int sr = tid >> 2, sc = tid & 3;
  const short* Ar0 = A + (size_t)(bm + sr) * K;
  const short* Ar1 = A + (size_t)(bm + sr + 64) * K;
  const short* Br0 = B + (size_t)(bn + sr) * K;
  const short* Br1 = B + (size_t)(bn + sr + 64) * K;

  short8 pa0 = *(const short8*)&Ar0[sc * 8];
  short8 pa1 = *(const short8*)&Ar1[sc * 8];
  short8 pb0 = *(const short8*)&Br0[sc * 8];
  short8 pb1 = *(const short8*)&Br1[sc * 8];

  int nk = K >> 5;
  for (int kt = 0; kt < nk; ++kt) {
    __syncthreads();
    *(short8*)&As[sr][sc * 8] = pa0;
    *(short8*)&As[sr + 64][sc * 8] = pa1;
    *(short8*)&Bs[sr][sc * 8] = pb0;
    *(short8*)&Bs[sr + 64][sc * 8] = pb1;
    if (kt + 1 < nk) {
      int ko = (kt + 1) * 32;
      pa0 = *(const short8*)&Ar0[ko + sc * 8];
      pa1 = *(const short8*)&Ar1[ko + sc * 8];
      pb0 = *(const short8*)&Br0[ko + sc * 8];
      pb1 = *(const short8*)&Br1[ko + sc * 8];
    }
    __syncthreads();
    short8 af[4], bf_[4];
#pragma unroll
    for (int mt = 0; mt < 4; ++mt)
      af[mt] = *(const short8*)&As[wm + mt * 16 + lr][lg * 8];
#pragma unroll
    for (int ntl = 0; ntl < 4; ++ntl)
      bf_[ntl] = *(const short8*)&Bs[wn + ntl * 16 + lr][lg * 8];
#pragma unroll
    for (int mt = 0; mt < 4; ++mt)
#pragma unroll
      for (int ntl = 0; ntl < 4; ++ntl)
        acc[mt][ntl] = __builtin_amdgcn_mfma_f32_16x16x32_bf16(af[mt], bf_[ntl], acc[mt][ntl], 0, 0, 0);
  }

#pragma unroll
  for (int mt = 0; mt < 4; ++mt)
#pragma unroll
    for (int ntl = 0; ntl < 4; ++ntl)
#pragma unroll
      for (int rr = 0; rr < 4; ++rr) {
        int m = bm + wm + mt * 16 + lg * 4 + rr;
        int n = bn + wn + ntl * 16 + lr;
        float val = acc[mt][ntl][rr];
        if (EPI == 0) {
          int b = m >> 11, s = m & 2047;
          int sel = n >> 10, hk = n & 1023;
          int h = hk >> 6, kd = hk & 63;
          // 0.125 * log2(e): logits in log2 domain -> exp2 in softmax
          if (sel == 0) Qo[((size_t)(b * 16 + h) * 2048 + s) * 64 + kd] = f2bf(val * 0.18033688011112042f);
          else if (sel == 1) Ko[((size_t)(b * 16 + h) * 2048 + s) * 64 + kd] = f2bf(val);
          else Vo[((size_t)(b * 16 + h) * 64 + kd) * 2048 + s] = f2bf(val);  // V^T
        } else {
          out[(size_t)m * 1024 + n] = val;
        }
      }
}

// ---------------- causal flash attention: no-max softmax + paired-tile ILP ----------------
// Q,K: [32][2048][64] bf16 (Q pre-scaled 1/8*log2e). VT: [32][64][2048]. O: [2][2048][1024] bf16.
// Tiles processed in PAIRS (64 kv rows per barrier interval): the two tiles' chains
// (QK -> exp2 -> pack -> PV) are independent -> 2x ILP; barriers halve (1 per pair,
// pair-level double buffer). Mask condition t >= qw covers diagonal AND the wave-0
// inactive last tile (fully masked -> p = 0 -> no contribution).
__global__ __launch_bounds__(128, 2) void k_attn(const short* __restrict__ Q,
                                                 const short* __restrict__ K,
                                                 const short* __restrict__ VT,
                                                 short* __restrict__ O) {
  const int S = 2048;
  int bh = blockIdx.x;
  int g = 31 - blockIdx.y;

  int tid = threadIdx.x;
  int wid = tid >> 6, lane = tid & 63;
  int hi = lane >> 5, ln = lane & 31;
  int qw = 2 * g + wid;
  int q_g = qw * 32 + ln;
  int npair = g + 1;

  __shared__ short Ks[2][2][32][64];
  __shared__ short Vs[2][2][64][32];

  const short* Qb = Q + (size_t)bh * S * 64;
  const short* Kb = K + (size_t)bh * S * 64;
  const short* Vb = VT + (size_t)bh * 64 * S;

  // Q fragments: B[k=d][col=q]
  short8 qf[4];
#pragma unroll
  for (int ds = 0; ds < 4; ++ds)
    qf[ds] = *(const short8*)&Qb[(size_t)q_g * 64 + ds * 16 + hi * 8];

  // staging thread mapping (block-wide)
  int kr = tid >> 2, kcb = tid & 3;          // K: row 0..31, chunks kcb, kcb+4
  int vd = tid >> 1, vcb = tid & 1;          // V: row d 0..63, chunks vcb, vcb+2
  const short* kgp = Kb + (size_t)kr * 64;
  const short* vgp = Vb + (size_t)vd * S;

  // prefetch pair 0 (tiles 0,1)
  short8 ka0 = *(const short8*)&kgp[kcb * 8];
  short8 ka1 = *(const short8*)&kgp[(kcb + 4) * 8];
  short8 kb0 = *(const short8*)&kgp[2048 + kcb * 8];
  short8 kb1 = *(const short8*)&kgp[2048 + (kcb + 4) * 8];
  short8 va0 = *(const short8*)&vgp[vcb * 8];
  short8 va1 = *(const short8*)&vgp[(vcb + 2) * 8];
  short8 vb0 = *(const short8*)&vgp[32 + vcb * 8];
  short8 vb1 = *(const short8*)&vgp[32 + (vcb + 2) * 8];

  f32x16 acoA = {}, acoB = {};
  float l = 0.f;

  for (int p = 0; p < npair; ++p) {
    int pb = p & 1;
    // stage both tiles of the pair (swizzled)
    *(short8*)&Ks[pb][0][kr][(kcb ^ (kr & 7)) * 8]       = ka0;
    *(short8*)&Ks[pb][0][kr][((kcb + 4) ^ (kr & 7)) * 8] = ka1;
    *(short8*)&Ks[pb][1][kr][(kcb ^ (kr & 7)) * 8]       = kb0;
    *(short8*)&Ks[pb][1][kr][((kcb + 4) ^ (kr & 7)) * 8] = kb1;
    *(short8*)&Vs[pb][0][vd][(vcb ^ (vd & 3)) * 8]       = va0;
    *(short8*)&Vs[pb][0][vd][((vcb + 2) ^ (vd & 3)) * 8] = va1;
    *(short8*)&Vs[pb][1][vd][(vcb ^ (vd & 3)) * 8]       = vb0;
    *(short8*)&Vs[pb][1][vd][((vcb + 2) ^ (vd & 3)) * 8] = vb1;
    // prefetch next pair (latency hides under compute)
    if (p + 1 < npair) {
      size_t ko0 = (size_t)(2 * p + 2) * 2048, ko1 = (size_t)(2 * p + 3) * 2048;
      size_t vo0 = (size_t)(2 * p + 2) * 32,   vo1 = (size_t)(2 * p + 3) * 32;
      ka0 = *(const short8*)&kgp[ko0 + kcb * 8];
      ka1 = *(const short8*)&kgp[ko0 + (kcb + 4) * 8];
      kb0 = *(const short8*)&kgp[ko1 + kcb * 8];
      kb1 = *(const short8*)&kgp[ko1 + (kcb + 4) * 8];
      va0 = *(const short8*)&vgp[vo0 + vcb * 8];
      va1 = *(const short8*)&vgp[vo0 + (vcb + 2) * 8];
      vb0 = *(const short8*)&vgp[vo1 + vcb * 8];
      vb1 = *(const short8*)&vgp[vo1 + (vcb + 2) * 8];
    }
    __syncthreads();

    int t0 = 2 * p, t1 = 2 * p + 1;

    // K fragments for both tiles
    short8 kc00 = *(const short8*)&Ks[pb][0][ln][((0 + hi) ^ (ln & 7)) * 8];
    short8 kc01 = *(const short8*)&Ks[pb][0][ln][((2 + hi) ^ (ln & 7)) * 8];
    short8 kc02 = *(const short8*)&Ks[pb][0][ln][((4 + hi) ^ (ln & 7)) * 8];
    short8 kc03 = *(const short8*)&Ks[pb][0][ln][((6 + hi) ^ (ln & 7)) * 8];
    short8 kc10 = *(const short8*)&Ks[pb][1][ln][((0 + hi) ^ (ln & 7)) * 8];
    short8 kc11 = *(const short8*)&Ks[pb][1][ln][((2 + hi) ^ (ln & 7)) * 8];
    short8 kc12 = *(const short8*)&Ks[pb][1][ln][((4 + hi) ^ (ln & 7)) * 8];
    short8 kc13 = *(const short8*)&Ks[pb][1][ln][((6 + hi) ^ (ln & 7)) * 8];

    f32x16 sa0 = {}, sa1 = {};
    __builtin_amdgcn_s_setprio(1);
    sa0 = __builtin_amdgcn_mfma_f32_32x32x16_bf16(kc00, qf[0], sa0, 0, 0, 0);
    sa1 = __builtin_amdgcn_mfma_f32_32x32x16_bf16(kc10, qf[0], sa1, 0, 0, 0);
    sa0 = __builtin_amdgcn_mfma_f32_32x32x16_bf16(kc01, qf[1], sa0, 0, 0, 0);
    sa1 = __builtin_amdgcn_mfma_f32_32x32x16_bf16(kc11, qf[1], sa1, 0, 0, 0);
    sa0 = __builtin_amdgcn_mfma_f32_32x32x16_bf16(kc02, qf[2], sa0, 0, 0, 0);
    sa1 = __builtin_amdgcn_mfma_f32_32x32x16_bf16(kc12, qf[2], sa1, 0, 0, 0);
    sa0 = __builtin_amdgcn_mfma_f32_32x32x16_bf16(kc03, qf[3], sa0, 0, 0, 0);
    sa1 = __builtin_amdgcn_mfma_f32_32x32x16_bf16(kc13, qf[3], sa1, 0, 0, 0);
    __builtin_amdgcn_s_setprio(0);

    // causal mask (t==qw: diagonal; t>qw: fully masked -> tile contributes nothing)
    if (t0 >= qw) {
#pragma unroll
      for (int r = 0; r < 16; ++r) {
        int kv_g = t0 * 32 + (r & 3) + 8 * (r >> 2) + 4 * hi;
        if (kv_g > q_g) sa0[r] = -1e30f;
      }
    }
    if (t1 >= qw) {
#pragma unroll
      for (int r = 0; r < 16; ++r) {
        int kv_g = t1 * 32 + (r & 3) + 8 * (r >> 2) + 4 * hi;
        if (kv_g > q_g) sa1[r] = -1e30f;
      }
    }

    // SM both tiles (independent chains; trans pipe overlaps the other tile's VALU)
    float p0[16], p1[16];
#pragma unroll
    for (int r = 0; r < 16; ++r) p0[r] = exp2f(sa0[r]);
#pragma unroll
    for (int r = 0; r < 16; ++r) p1[r] = exp2f(sa1[r]);
    {
      float s00 = (p0[0] + p0[1]) + (p0[2] + p0[3]);
      float s01 = (p0[4] + p0[5]) + (p0[6] + p0[7]);
      float s02 = (p0[8] + p0[9]) + (p0[10] + p0[11]);
      float s03 = (p0[12] + p0[13]) + (p0[14] + p0[15]);
      float s10 = (p1[0] + p1[1]) + (p1[2] + p1[3]);
      float s11 = (p1[4] + p1[5]) + (p1[6] + p1[7]);
      float s12 = (p1[8] + p1[9]) + (p1[10] + p1[11]);
      float s13 = (p1[12] + p1[13]) + (p1[14] + p1[15]);
      l += ((s00 + s01) + (s02 + s03)) + ((s10 + s11) + (s12 + s13));
    }

    // pack + PV tile 0
    {
      short8 v00 = *(const short8*)&Vs[pb][0][ln][((0 + hi) ^ (ln & 3)) * 8];
      short8 v01 = *(const short8*)&Vs[pb][0][ln][((2 + hi) ^ (ln & 3)) * 8];
      short8 v10 = *(const short8*)&Vs[pb][0][32 + ln][((0 + hi) ^ (ln & 3)) * 8];
      short8 v11 = *(const short8*)&Vs[pb][0][32 + ln][((2 + hi) ^ (ln & 3)) * 8];
#pragma unroll
      for (int s = 0; s < 2; ++s) {
        unsigned c0 = cvtpk(p0[8 * s + 0], p0[8 * s + 1]);
        unsigned c1 = cvtpk(p0[8 * s + 2], p0[8 * s + 3]);
        unsigned c2 = cvtpk(p0[8 * s + 4], p0[8 * s + 5]);
        unsigned c3 = cvtpk(p0[8 * s + 6], p0[8 * s + 7]);
        unsigned pc0 = (unsigned)__shfl_xor((int)c0, 32);
        unsigned pc1 = (unsigned)__shfl_xor((int)c1, 32);
        unsigned pc2 = (unsigned)__shfl_xor((int)c2, 32);
        unsigned pc3 = (unsigned)__shfl_xor((int)c3, 32);
        union { unsigned u[4]; short8 v; } pbv;
        pbv.u[0] = hi ? pc2 : c0;
        pbv.u[1] = hi ? pc3 : c1;
        pbv.u[2] = hi ? c2 : pc0;
        pbv.u[3] = hi ? c3 : pc1;
        __builtin_amdgcn_s_setprio(1);
        if (s == 0) {
          acoA = __builtin_amdgcn_mfma_f32_32x32x16_bf16(v00, pbv.v, acoA, 0, 0, 0);
          acoB = __builtin_amdgcn_mfma_f32_32x32x16_bf16(v10, pbv.v, acoB, 0, 0, 0);
        } else {
          acoA = __builtin_amdgcn_mfma_f32_32x32x16_bf16(v01, pbv.v, acoA, 0, 0, 0);
          acoB = __builtin_amdgcn_mfma_f32_32x32x16_bf16(v11, pbv.v, acoB, 0, 0, 0);
        }
        __builtin_amdgcn_s_setprio(0);
      }
    }
    // pack + PV tile 1
    {
      short8 v00 = *(const short8*)&Vs[pb][1][ln][((0 + hi) ^ (ln & 3)) * 8];
      short8 v01 = *(const short8*)&Vs[pb][1][ln][((2 + hi) ^ (ln & 3)) * 8];
      short8 v10 = *(const short8*)&Vs[pb][1][32 + ln][((0 + hi) ^ (ln & 3)) * 8];
      short8 v11 = *(const short8*)&Vs[pb][1][32 + ln][((2 + hi) ^ (ln & 3)) * 8];
#pragma unroll
      for (int s = 0; s < 2; ++s) {
        unsigned c0 = cvtpk(p1[8 * s + 0], p1[8 * s + 1]);
        unsigned c1 = cvtpk(p1[8 * s + 2], p1[8 * s + 3]);
        unsigned c2 = cvtpk(p1[8 * s + 4], p1[8 * s + 5]);
        unsigned c3 = cvtpk(p1[8 * s + 6], p1[8 * s + 7]);
        unsigned pc0 = (unsigned)__shfl_xor((int)c0, 32);
        unsigned pc1 = (unsigned)__shfl_xor((int)c1, 32);
        unsigned pc2 = (unsigned)__shfl_xor((int)c2, 32);
        unsigned pc3 = (unsigned)__shfl_xor((int)c3, 32);
        union { unsigned u[4]; short8 v; } pbv;
        pbv.u[0] = hi ? pc2 : c0;
        pbv.u[1] = hi ? pc3 : c1;
        pbv.u[2] = hi ? c2 : pc0;
        pbv.u[3] = hi ? c3 : pc1;
        __builtin_amdgcn_s_setprio(1);
        if (s == 0) {
          acoA = __builtin_amdgcn_mfma_f32_32x32x16_bf16(v00, pbv.v, acoA, 0, 0, 0);
          acoB = __builtin_amdgcn_mfma_f32_32x32x16_bf16(v10, pbv.v, acoB, 0, 0, 0);
        } else {
          acoA = __builtin_amdgcn_mfma_f32_32x32x16_bf16(v01, pbv.v, acoA, 0, 0, 0);
          acoB = __builtin_amdgcn_mfma_f32_32x32x16_bf16(v11, pbv.v, acoB, 0, 0, 0);
        }
        __builtin_amdgcn_s_setprio(0);
      }
    }
  }

  // merge the lane^32 pair's l once, normalize, store
  l += __shfl_xor(l, 32);
  float rl = 1.f / l;
  int b = bh >> 4, h = bh & 15;
  size_t obase = ((size_t)b * 2048 + q_g) * 1024 + h * 64;
#pragma unroll
  for (int g4 = 0; g4 < 4; ++g4) {
    int d0 = 8 * g4 + 4 * hi;
    *(unsigned*)&O[obase + d0]          = cvtpk(acoA[4 * g4] * rl, acoA[4 * g4 + 1] * rl);
    *(unsigned*)&O[obase + d0 + 2]      = cvtpk(acoA[4 * g4 + 2] * rl, acoA[4 * g4 + 3] * rl);
    *(unsigned*)&O[obase + 32 + d0]     = cvtpk(acoB[4 * g4] * rl, acoB[4 * g4 + 1] * rl);
    *(unsigned*)&O[obase + 32 + d0 + 2] = cvtpk(acoB[4 * g4 + 2] * rl, acoB[4 * g4 + 3] * rl);
  }
}

extern "C" void kernel_launch(void* const* d_in, const int* in_sizes, int n_in,
                              void* d_out, int out_size, void* d_ws, size_t ws_size,
                              hipStream_t stream) {
  const float* x  = (const float*)d_in[0];
  const float* wq = (const float*)d_in[1];
  const float* wk = (const float*)d_in[2];
  const float* wv = (const float*)d_in[3];
  const float* wo = (const float*)d_in[4];
  float* out = (float*)d_out;
  char* ws = (char*)d_ws;

  short* x_bf  = (short*)(ws);                       // 8 MB
  short* WqkvT = (short*)(ws + ((size_t)8 << 20));   // 6 MB
  short* wo_bf = (short*)(ws + ((size_t)14 << 20));  // 2 MB
  short* Qb    = (short*)(ws + ((size_t)16 << 20));  // 8 MB
  short* Kb    = (short*)(ws + ((size_t)24 << 20));  // 8 MB
  short* Vt    = (short*)(ws + ((size_t)32 << 20));  // 8 MB (V^T)
  short* Ob    = (short*)(ws + ((size_t)40 << 20));  // 8 MB

  k_cast<<<4096, 256, 0, stream>>>(x, x_bf, 1048576);
  k_cast<<<1024, 256, 0, stream>>>(wo, wo_bf, 262144);
  k_pack<<<dim3(16, 16, 3), 256, 0, stream>>>(wq, wk, wv, WqkvT);
  k_gemm<0><<<dim3(24, 32), 256, 0, stream>>>(x_bf, WqkvT, Qb, Kb, Vt, nullptr, 4096, 3072, 1024);
  k_attn<<<dim3(32, 32), 128, 0, stream>>>(Qb, Kb, Vt, Ob);
  k_gemm<1><<<dim3(8, 32), 256, 0, stream>>>(Ob, wo_bf, nullptr, nullptr, nullptr, out, 4096, 1024, 1024);
}

// Round 15
// 127.728 us; speedup vs baseline: 1.0841x; 1.0156x over previous
//
#include <hip/hip_runtime.h>
#include <hip/hip_bf16.h>

typedef __attribute__((ext_vector_type(4)))  float f32x4;
typedef __attribute__((ext_vector_type(16))) float f32x16;
typedef __attribute__((ext_vector_type(8)))  short short8;
typedef __attribute__((ext_vector_type(4)))  short short4v;

__device__ __forceinline__ short f2bf(float f) {
  union { float f; unsigned u; } x; x.f = f;
  unsigned r = (x.u + 0x7FFFu + ((x.u >> 16) & 1u)) >> 16;
  return (short)r;
}
__device__ __forceinline__ unsigned cvtpk(float lo, float hi) {
  unsigned r;
  asm("v_cvt_pk_bf16_f32 %0, %1, %2" : "=v"(r) : "v"(lo), "v"(hi));
  return r;
}
// async global->LDS, 16B per lane; LDS dest is wave-uniform base + lane*16
__device__ __forceinline__ void gload16(const short* g, short* l) {
  __builtin_amdgcn_global_load_lds((const __attribute__((address_space(1))) void*)g,
                                   (__attribute__((address_space(3))) void*)l, 16, 0, 0);
}

// ---------------- cast f32 -> bf16, vectorized x4 ----------------
__global__ __launch_bounds__(256) void k_cast(const float* __restrict__ in,
                                              short* __restrict__ out, int n4) {
  int i = blockIdx.x * 256 + threadIdx.x;
  if (i >= n4) return;
  f32x4 v = ((const f32x4*)in)[i];
  short4v s;
  s[0] = f2bf(v[0]); s[1] = f2bf(v[1]); s[2] = f2bf(v[2]); s[3] = f2bf(v[3]);
  ((short4v*)out)[i] = s;
}

// ---------------- pack w_q/w_k/w_v -> WqkvT bf16 [3072][1024] ----------------
__global__ __launch_bounds__(256) void k_pack(const float* __restrict__ wq,
                                              const float* __restrict__ wk,
                                              const float* __restrict__ wv,
                                              short* __restrict__ WT) {
  int nt = blockIdx.x, et = blockIdx.y, sel = blockIdx.z;
  const float* w = sel == 0 ? wq : (sel == 1 ? wk : wv);
  __shared__ float tile[64][65];
  int tid = threadIdx.x;
  int cl = tid & 63, rw = tid >> 6;
#pragma unroll
  for (int j = 0; j < 16; ++j) {
    int el = j * 4 + rw;
    tile[el][cl] = w[(size_t)(et * 64 + el) * 1024 + nt * 64 + cl];
  }
  __syncthreads();
#pragma unroll
  for (int j = 0; j < 16; ++j) {
    int nl = j * 4 + rw;
    int n = sel * 1024 + nt * 64 + nl;
    WT[(size_t)n * 1024 + et * 64 + cl] = f2bf(tile[cl][nl]);
  }
}

// ---------------- GEMM C[M][N] = A[M][K] * B^T[N][K], bf16 in, f32 acc ----------------
// Reg-staged prefetch (verified-fastest config for this problem size).
// EPI==0: scatter Q(*0.125*log2e)/K -> [BH][2048][64], V -> V^T [BH][64][2048]; EPI==1: f32 out
template <int EPI>
__global__ __launch_bounds__(256) void k_gemm(const short* __restrict__ A,
                                              const short* __restrict__ B,
                                              short* __restrict__ Qo, short* __restrict__ Ko,
                                              short* __restrict__ Vo, float* __restrict__ out,
                                              int M, int N, int K) {
  __shared__ short As[128][40];
  __shared__ short Bs[128][40];
  int tid = threadIdx.x;
  int bm = blockIdx.y * 128, bn = blockIdx.x * 128;
  int wid = tid >> 6, lane = tid & 63;
  int wm = (wid >> 1) * 64, wn = (wid & 1) * 64;
  int lg = lane >> 4, lr = lane & 15;
  f32x4 acc[4][4] = {};

  int sr = tid >> 2, sc = tid & 3;
  const short* Ar0 = A + (size_t)(bm + sr) * K;
  const short* Ar1 = A + (size_t)(bm + sr + 64) * K;
  const short* Br0 = B + (size_t)(bn + sr) * K;
  const short* Br1 = B + (size_t)(bn + sr + 64) * K;

  short8 pa0 = *(const short8*)&Ar0[sc * 8];
  short8 pa1 = *(const short8*)&Ar1[sc * 8];
  short8 pb0 = *(const short8*)&Br0[sc * 8];
  short8 pb1 = *(const short8*)&Br1[sc * 8];

  int nk = K >> 5;
  for (int kt = 0; kt < nk; ++kt) {
    __syncthreads();
    *(short8*)&As[sr][sc * 8] = pa0;
    *(short8*)&As[sr + 64][sc * 8] = pa1;
    *(short8*)&Bs[sr][sc * 8] = pb0;
    *(short8*)&Bs[sr + 64][sc * 8] = pb1;
    if (kt + 1 < nk) {
      int ko = (kt + 1) * 32;
      pa0 = *(const short8*)&Ar0[ko + sc * 8];
      pa1 = *(const short8*)&Ar1[ko + sc * 8];
      pb0 = *(const short8*)&Br0[ko + sc * 8];
      pb1 = *(const short8*)&Br1[ko + sc * 8];
    }
    __syncthreads();
    short8 af[4], bf_[4];
#pragma unroll
    for (int mt = 0; mt < 4; ++mt)
      af[mt] = *(const short8*)&As[wm + mt * 16 + lr][lg * 8];
#pragma unroll
    for (int ntl = 0; ntl < 4; ++ntl)
      bf_[ntl] = *(const short8*)&Bs[wn + ntl * 16 + lr][lg * 8];
#pragma unroll
    for (int mt = 0; mt < 4; ++mt)
#pragma unroll
      for (int ntl = 0; ntl < 4; ++ntl)
        acc[mt][ntl] = __builtin_amdgcn_mfma_f32_16x16x32_bf16(af[mt], bf_[ntl], acc[mt][ntl], 0, 0, 0);
  }

#pragma unroll
  for (int mt = 0; mt < 4; ++mt)
#pragma unroll
    for (int ntl = 0; ntl < 4; ++ntl) {
      int m0 = bm + wm + mt * 16 + lg * 4;
      int n = bn + wn + ntl * 16 + lr;
      if (EPI == 0) {
        int b = m0 >> 11, s0 = m0 & 2047;
        int sel = n >> 10, hk = n & 1023;
        int h = hk >> 6, kd = hk & 63;
        if (sel == 0) {
#pragma unroll
          for (int rr = 0; rr < 4; ++rr)
            Qo[((size_t)(b * 16 + h) * 2048 + s0 + rr) * 64 + kd] =
                f2bf(acc[mt][ntl][rr] * 0.18033688011112042f);  // 0.125*log2e
        } else if (sel == 1) {
#pragma unroll
          for (int rr = 0; rr < 4; ++rr)
            Ko[((size_t)(b * 16 + h) * 2048 + s0 + rr) * 64 + kd] = f2bf(acc[mt][ntl][rr]);
        } else {
          short4v v4;
#pragma unroll
          for (int rr = 0; rr < 4; ++rr) v4[rr] = f2bf(acc[mt][ntl][rr]);
          *(short4v*)&Vo[((size_t)(b * 16 + h) * 64 + kd) * 2048 + s0] = v4;  // V^T, 8B store
        }
      } else {
#pragma unroll
        for (int rr = 0; rr < 4; ++rr)
          out[(size_t)(m0 + rr) * 1024 + n] = acc[mt][ntl][rr];
      }
    }
}

// ---------------- causal flash attention: no-max SM + paired ILP + gload_lds staging --------
// Q,K: [32][2048][64] bf16 (Q pre-scaled 1/8*log2e). VT: [32][64][2048]. O: [2][2048][1024] bf16.
// Staging: global_load_lds with the XOR swizzle folded into the per-lane GLOBAL source
// address (LDS dest linear — rule: both-sides-or-neither). 8 loads per pair issued after the
// top barrier; ~1000-cyc compute phase covers the latency; one vmcnt(0)+barrier per pair.
// ds_read side identical to the verified round-14 kernel.
__global__ __launch_bounds__(128, 2) void k_attn(const short* __restrict__ Q,
                                                 const short* __restrict__ K,
                                                 const short* __restrict__ VT,
                                                 short* __restrict__ O) {
  const int S = 2048;
  int bh = blockIdx.x;
  int g = 31 - blockIdx.y;  // LPT: longest first

  int tid = threadIdx.x;
  int wid = tid >> 6, lane = tid & 63;
  int hi = lane >> 5, ln = lane & 31;
  int qw = 2 * g + wid;
  int q_g = qw * 32 + ln;
  int npair = g + 1;

  __shared__ short Ks[2][2][32 * 64];
  __shared__ short Vs[2][2][64 * 32];

  const short* Qb = Q + (size_t)bh * S * 64;
  const short* Kb = K + (size_t)bh * S * 64;
  const short* Vb = VT + (size_t)bh * 64 * S;

  // Q fragments: B[k=d][col=q]
  short8 qf[4];
#pragma unroll
  for (int ds = 0; ds < 4; ++ds)
    qf[ds] = *(const short8*)&Qb[(size_t)q_g * 64 + ds * 16 + hi * 8];

  // per-lane staging sources, swizzle folded in (LDS dest stays linear):
  // K tile [32][64]: wave w inst j covers LDS bytes (j*2+w)*1024 + lane*16
  //   -> row s = (j*2+w)*8 + (lane>>3), chunk c = lane&7; source chunk = c ^ (s&7)
  int ksr0 = wid * 8 + (lane >> 3);
  int kc = lane & 7;
  const short* kSrc0 = Kb + ksr0 * 64 + ((kc ^ (ksr0 & 7)) * 8);
  int ksr1 = ksr0 + 16;
  const short* kSrc1 = Kb + ksr1 * 64 + ((kc ^ (ksr1 & 7)) * 8);
  // V tile [64][32]: row d = (j*2+w)*16 + (lane>>2), chunk c = lane&3; source chunk = c ^ (d&3)
  int vdr0 = wid * 16 + (lane >> 2);
  int vc = lane & 3;
  const short* vSrc0 = Vb + (size_t)vdr0 * S + ((vc ^ (vdr0 & 3)) * 8);
  int vdr1 = vdr0 + 32;
  const short* vSrc1 = Vb + (size_t)vdr1 * S + ((vc ^ (vdr1 & 3)) * 8);

  f32x16 acoA = {}, acoB = {};
  float l = 0.f;

#define STAGE_PAIR(pbuf, t0)                                                    \
  {                                                                             \
    short* kd0 = &Ks[pbuf][0][0] + wid * 512;                                   \
    short* kd1 = &Ks[pbuf][1][0] + wid * 512;                                   \
    short* vdp0 = &Vs[pbuf][0][0] + wid * 512;                                  \
    short* vdp1 = &Vs[pbuf][1][0] + wid * 512;                                  \
    size_t ko = (size_t)(t0) * 2048;                                            \
    size_t vo = (size_t)(t0) * 32;                                              \
    gload16(kSrc0 + ko, kd0);                                                   \
    gload16(kSrc1 + ko, kd0 + 1024);                                            \
    gload16(kSrc0 + ko + 2048, kd1);                                            \
    gload16(kSrc1 + ko + 2048, kd1 + 1024);                                     \
    gload16(vSrc0 + vo, vdp0);                                                  \
    gload16(vSrc1 + vo, vdp0 + 1024);                                           \
    gload16(vSrc0 + vo + 32, vdp1);                                             \
    gload16(vSrc1 + vo + 32, vdp1 + 1024);                                      \
  }

  // prologue: stage pair 0, drain, barrier
  STAGE_PAIR(0, 0)
  asm volatile("s_waitcnt vmcnt(0)" ::: "memory");
  __builtin_amdgcn_s_barrier();

  for (int p = 0; p < npair; ++p) {
    int pb = p & 1;
    // issue next pair's staging (in flight across the whole compute phase)
    if (p + 1 < npair) STAGE_PAIR(pb ^ 1, 2 * p + 2)

    int t0 = 2 * p, t1 = 2 * p + 1;

    // K fragments for both tiles
    short8 kc00 = *(const short8*)&Ks[pb][0][ln * 64 + (((0 + hi) ^ (ln & 7)) * 8)];
    short8 kc01 = *(const short8*)&Ks[pb][0][ln * 64 + (((2 + hi) ^ (ln & 7)) * 8)];
    short8 kc02 = *(const short8*)&Ks[pb][0][ln * 64 + (((4 + hi) ^ (ln & 7)) * 8)];
    short8 kc03 = *(const short8*)&Ks[pb][0][ln * 64 + (((6 + hi) ^ (ln & 7)) * 8)];
    short8 kc10 = *(const short8*)&Ks[pb][1][ln * 64 + (((0 + hi) ^ (ln & 7)) * 8)];
    short8 kc11 = *(const short8*)&Ks[pb][1][ln * 64 + (((2 + hi) ^ (ln & 7)) * 8)];
    short8 kc12 = *(const short8*)&Ks[pb][1][ln * 64 + (((4 + hi) ^ (ln & 7)) * 8)];
    short8 kc13 = *(const short8*)&Ks[pb][1][ln * 64 + (((6 + hi) ^ (ln & 7)) * 8)];

    f32x16 sa0 = {}, sa1 = {};
    __builtin_amdgcn_s_setprio(1);
    sa0 = __builtin_amdgcn_mfma_f32_32x32x16_bf16(kc00, qf[0], sa0, 0, 0, 0);
    sa1 = __builtin_amdgcn_mfma_f32_32x32x16_bf16(kc10, qf[0], sa1, 0, 0, 0);
    sa0 = __builtin_amdgcn_mfma_f32_32x32x16_bf16(kc01, qf[1], sa0, 0, 0, 0);
    sa1 = __builtin_amdgcn_mfma_f32_32x32x16_bf16(kc11, qf[1], sa1, 0, 0, 0);
    sa0 = __builtin_amdgcn_mfma_f32_32x32x16_bf16(kc02, qf[2], sa0, 0, 0, 0);
    sa1 = __builtin_amdgcn_mfma_f32_32x32x16_bf16(kc12, qf[2], sa1, 0, 0, 0);
    sa0 = __builtin_amdgcn_mfma_f32_32x32x16_bf16(kc03, qf[3], sa0, 0, 0, 0);
    sa1 = __builtin_amdgcn_mfma_f32_32x32x16_bf16(kc13, qf[3], sa1, 0, 0, 0);
    __builtin_amdgcn_s_setprio(0);

    // causal mask (t==qw: diagonal; t>qw: fully masked -> contributes nothing)
    if (t0 >= qw) {
#pragma unroll
      for (int r = 0; r < 16; ++r) {
        int kv_g = t0 * 32 + (r & 3) + 8 * (r >> 2) + 4 * hi;
        if (kv_g > q_g) sa0[r] = -1e30f;
      }
    }
    if (t1 >= qw) {
#pragma unroll
      for (int r = 0; r < 16; ++r) {
        int kv_g = t1 * 32 + (r & 3) + 8 * (r >> 2) + 4 * hi;
        if (kv_g > q_g) sa1[r] = -1e30f;
      }
    }

    // no-max softmax, both tiles (independent chains)
    float p0[16], p1[16];
#pragma unroll
    for (int r = 0; r < 16; ++r) p0[r] = exp2f(sa0[r]);
#pragma unroll
    for (int r = 0; r < 16; ++r) p1[r] = exp2f(sa1[r]);
    {
      float s00 = (p0[0] + p0[1]) + (p0[2] + p0[3]);
      float s01 = (p0[4] + p0[5]) + (p0[6] + p0[7]);
      float s02 = (p0[8] + p0[9]) + (p0[10] + p0[11]);
      float s03 = (p0[12] + p0[13]) + (p0[14] + p0[15]);
      float s10 = (p1[0] + p1[1]) + (p1[2] + p1[3]);
      float s11 = (p1[4] + p1[5]) + (p1[6] + p1[7]);
      float s12 = (p1[8] + p1[9]) + (p1[10] + p1[11]);
      float s13 = (p1[12] + p1[13]) + (p1[14] + p1[15]);
      l += ((s00 + s01) + (s02 + s03)) + ((s10 + s11) + (s12 + s13));
    }

    // pack + PV tile 0
    {
      short8 v00 = *(const short8*)&Vs[pb][0][ln * 32 + (((0 + hi) ^ (ln & 3)) * 8)];
      short8 v01 = *(const short8*)&Vs[pb][0][ln * 32 + (((2 + hi) ^ (ln & 3)) * 8)];
      short8 v10 = *(const short8*)&Vs[pb][0][(32 + ln) * 32 + (((0 + hi) ^ (ln & 3)) * 8)];
      short8 v11 = *(const short8*)&Vs[pb][0][(32 + ln) * 32 + (((2 + hi) ^ (ln & 3)) * 8)];
#pragma unroll
      for (int s = 0; s < 2; ++s) {
        unsigned c0 = cvtpk(p0[8 * s + 0], p0[8 * s + 1]);
        unsigned c1 = cvtpk(p0[8 * s + 2], p0[8 * s + 3]);
        unsigned c2 = cvtpk(p0[8 * s + 4], p0[8 * s + 5]);
        unsigned c3 = cvtpk(p0[8 * s + 6], p0[8 * s + 7]);
        unsigned pc0 = (unsigned)__shfl_xor((int)c0, 32);
        unsigned pc1 = (unsigned)__shfl_xor((int)c1, 32);
        unsigned pc2 = (unsigned)__shfl_xor((int)c2, 32);
        unsigned pc3 = (unsigned)__shfl_xor((int)c3, 32);
        union { unsigned u[4]; short8 v; } pbv;
        pbv.u[0] = hi ? pc2 : c0;
        pbv.u[1] = hi ? pc3 : c1;
        pbv.u[2] = hi ? c2 : pc0;
        pbv.u[3] = hi ? c3 : pc1;
        __builtin_amdgcn_s_setprio(1);
        if (s == 0) {
          acoA = __builtin_amdgcn_mfma_f32_32x32x16_bf16(v00, pbv.v, acoA, 0, 0, 0);
          acoB = __builtin_amdgcn_mfma_f32_32x32x16_bf16(v10, pbv.v, acoB, 0, 0, 0);
        } else {
          acoA = __builtin_amdgcn_mfma_f32_32x32x16_bf16(v01, pbv.v, acoA, 0, 0, 0);
          acoB = __builtin_amdgcn_mfma_f32_32x32x16_bf16(v11, pbv.v, acoB, 0, 0, 0);
        }
        __builtin_amdgcn_s_setprio(0);
      }
    }
    // pack + PV tile 1
    {
      short8 v00 = *(const short8*)&Vs[pb][1][ln * 32 + (((0 + hi) ^ (ln & 3)) * 8)];
      short8 v01 = *(const short8*)&Vs[pb][1][ln * 32 + (((2 + hi) ^ (ln & 3)) * 8)];
      short8 v10 = *(const short8*)&Vs[pb][1][(32 + ln) * 32 + (((0 + hi) ^ (ln & 3)) * 8)];
      short8 v11 = *(const short8*)&Vs[pb][1][(32 + ln) * 32 + (((2 + hi) ^ (ln & 3)) * 8)];
#pragma unroll
      for (int s = 0; s < 2; ++s) {
        unsigned c0 = cvtpk(p1[8 * s + 0], p1[8 * s + 1]);
        unsigned c1 = cvtpk(p1[8 * s + 2], p1[8 * s + 3]);
        unsigned c2 = cvtpk(p1[8 * s + 4], p1[8 * s + 5]);
        unsigned c3 = cvtpk(p1[8 * s + 6], p1[8 * s + 7]);
        unsigned pc0 = (unsigned)__shfl_xor((int)c0, 32);
        unsigned pc1 = (unsigned)__shfl_xor((int)c1, 32);
        unsigned pc2 = (unsigned)__shfl_xor((int)c2, 32);
        unsigned pc3 = (unsigned)__shfl_xor((int)c3, 32);
        union { unsigned u[4]; short8 v; } pbv;
        pbv.u[0] = hi ? pc2 : c0;
        pbv.u[1] = hi ? pc3 : c1;
        pbv.u[2] = hi ? c2 : pc0;
        pbv.u[3] = hi ? c3 : pc1;
        __builtin_amdgcn_s_setprio(1);
        if (s == 0) {
          acoA = __builtin_amdgcn_mfma_f32_32x32x16_bf16(v00, pbv.v, acoA, 0, 0, 0);
          acoB = __builtin_amdgcn_mfma_f32_32x32x16_bf16(v10, pbv.v, acoB, 0, 0, 0);
        } else {
          acoA = __builtin_amdgcn_mfma_f32_32x32x16_bf16(v01, pbv.v, acoA, 0, 0, 0);
          acoB = __builtin_amdgcn_mfma_f32_32x32x16_bf16(v11, pbv.v, acoB, 0, 0, 0);
        }
        __builtin_amdgcn_s_setprio(0);
      }
    }

    // drain next pair's in-flight loads AFTER compute, then barrier
    asm volatile("s_waitcnt vmcnt(0)" ::: "memory");
    __builtin_amdgcn_s_barrier();
  }
#undef STAGE_PAIR

  // merge the lane^32 pair's l once, normalize, store
  l += __shfl_xor(l, 32);
  float rl = 1.f / l;
  int b = bh >> 4, h = bh & 15;
  size_t obase = ((size_t)b * 2048 + q_g) * 1024 + h * 64;
#pragma unroll
  for (int g4 = 0; g4 < 4; ++g4) {
    int d0 = 8 * g4 + 4 * hi;
    *(unsigned*)&O[obase + d0]          = cvtpk(acoA[4 * g4] * rl, acoA[4 * g4 + 1] * rl);
    *(unsigned*)&O[obase + d0 + 2]      = cvtpk(acoA[4 * g4 + 2] * rl, acoA[4 * g4 + 3] * rl);
    *(unsigned*)&O[obase + 32 + d0]     = cvtpk(acoB[4 * g4] * rl, acoB[4 * g4 + 1] * rl);
    *(unsigned*)&O[obase + 32 + d0 + 2] = cvtpk(acoB[4 * g4 + 2] * rl, acoB[4 * g4 + 3] * rl);
  }
}

extern "C" void kernel_launch(void* const* d_in, const int* in_sizes, int n_in,
                              void* d_out, int out_size, void* d_ws, size_t ws_size,
                              hipStream_t stream) {
  const float* x  = (const float*)d_in[0];
  const float* wq = (const float*)d_in[1];
  const float* wk = (const float*)d_in[2];
  const float* wv = (const float*)d_in[3];
  const float* wo = (const float*)d_in[4];
  float* out = (float*)d_out;
  char* ws = (char*)d_ws;

  short* x_bf  = (short*)(ws);                       // 8 MB
  short* WqkvT = (short*)(ws + ((size_t)8 << 20));   // 6 MB
  short* wo_bf = (short*)(ws + ((size_t)14 << 20));  // 2 MB
  short* Qb    = (short*)(ws + ((size_t)16 << 20));  // 8 MB
  short* Kb    = (short*)(ws + ((size_t)24 << 20));  // 8 MB
  short* Vt    = (short*)(ws + ((size_t)32 << 20));  // 8 MB (V^T)
  short* Ob    = (short*)(ws + ((size_t)40 << 20));  // 8 MB

  k_cast<<<4096, 256, 0, stream>>>(x, x_bf, 1048576);
  k_cast<<<1024, 256, 0, stream>>>(wo, wo_bf, 262144);
  k_pack<<<dim3(16, 16, 3), 256, 0, stream>>>(wq, wk, wv, WqkvT);
  k_gemm<0><<<dim3(24, 32), 256, 0, stream>>>(x_bf, WqkvT, Qb, Kb, Vt, nullptr, 4096, 3072, 1024);
  k_attn<<<dim3(32, 32), 128, 0, stream>>>(Qb, Kb, Vt, Ob);
  k_gemm<1><<<dim3(8, 32), 256, 0, stream>>>(Ob, wo_bf, nullptr, nullptr, nullptr, out, 4096, 1024, 1024);
}

// Round 16
// 122.673 us; speedup vs baseline: 1.1288x; 1.0412x over previous
//
#include <hip/hip_runtime.h>
#include <hip/hip_bf16.h>

typedef __attribute__((ext_vector_type(4)))  float f32x4;
typedef __attribute__((ext_vector_type(16))) float f32x16;
typedef __attribute__((ext_vector_type(8)))  short short8;
typedef __attribute__((ext_vector_type(4)))  short short4v;

__device__ __forceinline__ short f2bf(float f) {
  union { float f; unsigned u; } x; x.f = f;
  unsigned r = (x.u + 0x7FFFu + ((x.u >> 16) & 1u)) >> 16;
  return (short)r;
}
__device__ __forceinline__ unsigned cvtpk(float lo, float hi) {
  unsigned r;
  asm("v_cvt_pk_bf16_f32 %0, %1, %2" : "=v"(r) : "v"(lo), "v"(hi));
  return r;
}

// ---------------- cast f32 -> bf16, vectorized x4 ----------------
__global__ __launch_bounds__(256) void k_cast(const float* __restrict__ in,
                                              short* __restrict__ out, int n4) {
  int i = blockIdx.x * 256 + threadIdx.x;
  if (i >= n4) return;
  f32x4 v = ((const f32x4*)in)[i];
  short4v s;
  s[0] = f2bf(v[0]); s[1] = f2bf(v[1]); s[2] = f2bf(v[2]); s[3] = f2bf(v[3]);
  ((short4v*)out)[i] = s;
}

// ---------------- pack w_q/w_k/w_v -> WqkvT bf16 [3072][1024] ----------------
__global__ __launch_bounds__(256) void k_pack(const float* __restrict__ wq,
                                              const float* __restrict__ wk,
                                              const float* __restrict__ wv,
                                              short* __restrict__ WT) {
  int nt = blockIdx.x, et = blockIdx.y, sel = blockIdx.z;
  const float* w = sel == 0 ? wq : (sel == 1 ? wk : wv);
  __shared__ float tile[64][65];
  int tid = threadIdx.x;
  int cl = tid & 63, rw = tid >> 6;
#pragma unroll
  for (int j = 0; j < 16; ++j) {
    int el = j * 4 + rw;
    tile[el][cl] = w[(size_t)(et * 64 + el) * 1024 + nt * 64 + cl];
  }
  __syncthreads();
#pragma unroll
  for (int j = 0; j < 16; ++j) {
    int nl = j * 4 + rw;
    int n = sel * 1024 + nt * 64 + nl;
    WT[(size_t)n * 1024 + et * 64 + cl] = f2bf(tile[cl][nl]);
  }
}

// ---------------- GEMM C[M][N] = A[M][K] * B^T[N][K], bf16 in, f32 acc ----------------
// Reg-staged prefetch; vectorized V^T epilogue (8B stores) — both verified-fastest.
// EPI==0: scatter Q(*0.125*log2e)/K -> [BH][2048][64], V -> V^T [BH][64][2048]; EPI==1: f32 out
template <int EPI>
__global__ __launch_bounds__(256) void k_gemm(const short* __restrict__ A,
                                              const short* __restrict__ B,
                                              short* __restrict__ Qo, short* __restrict__ Ko,
                                              short* __restrict__ Vo, float* __restrict__ out,
                                              int M, int N, int K) {
  __shared__ short As[128][40];
  __shared__ short Bs[128][40];
  int tid = threadIdx.x;
  int bm = blockIdx.y * 128, bn = blockIdx.x * 128;
  int wid = tid >> 6, lane = tid & 63;
  int wm = (wid >> 1) * 64, wn = (wid & 1) * 64;
  int lg = lane >> 4, lr = lane & 15;
  f32x4 acc[4][4] = {};

  int sr = tid >> 2, sc = tid & 3;
  const short* Ar0 = A + (size_t)(bm + sr) * K;
  const short* Ar1 = A + (size_t)(bm + sr + 64) * K;
  const short* Br0 = B + (size_t)(bn + sr) * K;
  const short* Br1 = B + (size_t)(bn + sr + 64) * K;

  short8 pa0 = *(const short8*)&Ar0[sc * 8];
  short8 pa1 = *(const short8*)&Ar1[sc * 8];
  short8 pb0 = *(const short8*)&Br0[sc * 8];
  short8 pb1 = *(const short8*)&Br1[sc * 8];

  int nk = K >> 5;
  for (int kt = 0; kt < nk; ++kt) {
    __syncthreads();
    *(short8*)&As[sr][sc * 8] = pa0;
    *(short8*)&As[sr + 64][sc * 8] = pa1;
    *(short8*)&Bs[sr][sc * 8] = pb0;
    *(short8*)&Bs[sr + 64][sc * 8] = pb1;
    if (kt + 1 < nk) {
      int ko = (kt + 1) * 32;
      pa0 = *(const short8*)&Ar0[ko + sc * 8];
      pa1 = *(const short8*)&Ar1[ko + sc * 8];
      pb0 = *(const short8*)&Br0[ko + sc * 8];
      pb1 = *(const short8*)&Br1[ko + sc * 8];
    }
    __syncthreads();
    short8 af[4], bf_[4];
#pragma unroll
    for (int mt = 0; mt < 4; ++mt)
      af[mt] = *(const short8*)&As[wm + mt * 16 + lr][lg * 8];
#pragma unroll
    for (int ntl = 0; ntl < 4; ++ntl)
      bf_[ntl] = *(const short8*)&Bs[wn + ntl * 16 + lr][lg * 8];
#pragma unroll
    for (int mt = 0; mt < 4; ++mt)
#pragma unroll
      for (int ntl = 0; ntl < 4; ++ntl)
        acc[mt][ntl] = __builtin_amdgcn_mfma_f32_16x16x32_bf16(af[mt], bf_[ntl], acc[mt][ntl], 0, 0, 0);
  }

#pragma unroll
  for (int mt = 0; mt < 4; ++mt)
#pragma unroll
    for (int ntl = 0; ntl < 4; ++ntl) {
      int m0 = bm + wm + mt * 16 + lg * 4;
      int n = bn + wn + ntl * 16 + lr;
      if (EPI == 0) {
        int b = m0 >> 11, s0 = m0 & 2047;
        int sel = n >> 10, hk = n & 1023;
        int h = hk >> 6, kd = hk & 63;
        if (sel == 0) {
#pragma unroll
          for (int rr = 0; rr < 4; ++rr)
            Qo[((size_t)(b * 16 + h) * 2048 + s0 + rr) * 64 + kd] =
                f2bf(acc[mt][ntl][rr] * 0.18033688011112042f);  // 0.125*log2e
        } else if (sel == 1) {
#pragma unroll
          for (int rr = 0; rr < 4; ++rr)
            Ko[((size_t)(b * 16 + h) * 2048 + s0 + rr) * 64 + kd] = f2bf(acc[mt][ntl][rr]);
        } else {
          short4v v4;
#pragma unroll
          for (int rr = 0; rr < 4; ++rr) v4[rr] = f2bf(acc[mt][ntl][rr]);
          *(short4v*)&Vo[((size_t)(b * 16 + h) * 64 + kd) * 2048 + s0] = v4;  // V^T, 8B store
        }
      } else {
#pragma unroll
        for (int rr = 0; rr < 4; ++rr)
          out[(size_t)(m0 + rr) * 1024 + n] = acc[mt][ntl][rr];
      }
    }
}

// ---------------- causal flash attention: no-max softmax + paired-tile ILP ----------------
// (round-14 verified config: reg-staged prefetch, 58.6 us)
// Q,K: [32][2048][64] bf16 (Q pre-scaled 1/8*log2e). VT: [32][64][2048]. O: [2][2048][1024] bf16.
__global__ __launch_bounds__(128, 2) void k_attn(const short* __restrict__ Q,
                                                 const short* __restrict__ K,
                                                 const short* __restrict__ VT,
                                                 short* __restrict__ O) {
  const int S = 2048;
  int bh = blockIdx.x;
  int g = 31 - blockIdx.y;

  int tid = threadIdx.x;
  int wid = tid >> 6, lane = tid & 63;
  int hi = lane >> 5, ln = lane & 31;
  int qw = 2 * g + wid;
  int q_g = qw * 32 + ln;
  int npair = g + 1;

  __shared__ short Ks[2][2][32][64];
  __shared__ short Vs[2][2][64][32];

  const short* Qb = Q + (size_t)bh * S * 64;
  const short* Kb = K + (size_t)bh * S * 64;
  const short* Vb = VT + (size_t)bh * 64 * S;

  // Q fragments: B[k=d][col=q]
  short8 qf[4];
#pragma unroll
  for (int ds = 0; ds < 4; ++ds)
    qf[ds] = *(const short8*)&Qb[(size_t)q_g * 64 + ds * 16 + hi * 8];

  // staging thread mapping (block-wide)
  int kr = tid >> 2, kcb = tid & 3;          // K: row 0..31, chunks kcb, kcb+4
  int vd = tid >> 1, vcb = tid & 1;          // V: row d 0..63, chunks vcb, vcb+2
  const short* kgp = Kb + (size_t)kr * 64;
  const short* vgp = Vb + (size_t)vd * S;

  // prefetch pair 0 (tiles 0,1)
  short8 ka0 = *(const short8*)&kgp[kcb * 8];
  short8 ka1 = *(const short8*)&kgp[(kcb + 4) * 8];
  short8 kb0 = *(const short8*)&kgp[2048 + kcb * 8];
  short8 kb1 = *(const short8*)&kgp[2048 + (kcb + 4) * 8];
  short8 va0 = *(const short8*)&vgp[vcb * 8];
  short8 va1 = *(const short8*)&vgp[(vcb + 2) * 8];
  short8 vb0 = *(const short8*)&vgp[32 + vcb * 8];
  short8 vb1 = *(const short8*)&vgp[32 + (vcb + 2) * 8];

  f32x16 acoA = {}, acoB = {};
  float l = 0.f;

  for (int p = 0; p < npair; ++p) {
    int pb = p & 1;
    // stage both tiles of the pair (swizzled)
    *(short8*)&Ks[pb][0][kr][(kcb ^ (kr & 7)) * 8]       = ka0;
    *(short8*)&Ks[pb][0][kr][((kcb + 4) ^ (kr & 7)) * 8] = ka1;
    *(short8*)&Ks[pb][1][kr][(kcb ^ (kr & 7)) * 8]       = kb0;
    *(short8*)&Ks[pb][1][kr][((kcb + 4) ^ (kr & 7)) * 8] = kb1;
    *(short8*)&Vs[pb][0][vd][(vcb ^ (vd & 3)) * 8]       = va0;
    *(short8*)&Vs[pb][0][vd][((vcb + 2) ^ (vd & 3)) * 8] = va1;
    *(short8*)&Vs[pb][1][vd][(vcb ^ (vd & 3)) * 8]       = vb0;
    *(short8*)&Vs[pb][1][vd][((vcb + 2) ^ (vd & 3)) * 8] = vb1;
    // prefetch next pair (latency hides under compute)
    if (p + 1 < npair) {
      size_t ko0 = (size_t)(2 * p + 2) * 2048, ko1 = (size_t)(2 * p + 3) * 2048;
      size_t vo0 = (size_t)(2 * p + 2) * 32,   vo1 = (size_t)(2 * p + 3) * 32;
      ka0 = *(const short8*)&kgp[ko0 + kcb * 8];
      ka1 = *(const short8*)&kgp[ko0 + (kcb + 4) * 8];
      kb0 = *(const short8*)&kgp[ko1 + kcb * 8];
      kb1 = *(const short8*)&kgp[ko1 + (kcb + 4) * 8];
      va0 = *(const short8*)&vgp[vo0 + vcb * 8];
      va1 = *(const short8*)&vgp[vo0 + (vcb + 2) * 8];
      vb0 = *(const short8*)&vgp[vo1 + vcb * 8];
      vb1 = *(const short8*)&vgp[vo1 + (vcb + 2) * 8];
    }
    __syncthreads();

    int t0 = 2 * p, t1 = 2 * p + 1;

    // K fragments for both tiles
    short8 kc00 = *(const short8*)&Ks[pb][0][ln][((0 + hi) ^ (ln & 7)) * 8];
    short8 kc01 = *(const short8*)&Ks[pb][0][ln][((2 + hi) ^ (ln & 7)) * 8];
    short8 kc02 = *(const short8*)&Ks[pb][0][ln][((4 + hi) ^ (ln & 7)) * 8];
    short8 kc03 = *(const short8*)&Ks[pb][0][ln][((6 + hi) ^ (ln & 7)) * 8];
    short8 kc10 = *(const short8*)&Ks[pb][1][ln][((0 + hi) ^ (ln & 7)) * 8];
    short8 kc11 = *(const short8*)&Ks[pb][1][ln][((2 + hi) ^ (ln & 7)) * 8];
    short8 kc12 = *(const short8*)&Ks[pb][1][ln][((4 + hi) ^ (ln & 7)) * 8];
    short8 kc13 = *(const short8*)&Ks[pb][1][ln][((6 + hi) ^ (ln & 7)) * 8];

    f32x16 sa0 = {}, sa1 = {};
    __builtin_amdgcn_s_setprio(1);
    sa0 = __builtin_amdgcn_mfma_f32_32x32x16_bf16(kc00, qf[0], sa0, 0, 0, 0);
    sa1 = __builtin_amdgcn_mfma_f32_32x32x16_bf16(kc10, qf[0], sa1, 0, 0, 0);
    sa0 = __builtin_amdgcn_mfma_f32_32x32x16_bf16(kc01, qf[1], sa0, 0, 0, 0);
    sa1 = __builtin_amdgcn_mfma_f32_32x32x16_bf16(kc11, qf[1], sa1, 0, 0, 0);
    sa0 = __builtin_amdgcn_mfma_f32_32x32x16_bf16(kc02, qf[2], sa0, 0, 0, 0);
    sa1 = __builtin_amdgcn_mfma_f32_32x32x16_bf16(kc12, qf[2], sa1, 0, 0, 0);
    sa0 = __builtin_amdgcn_mfma_f32_32x32x16_bf16(kc03, qf[3], sa0, 0, 0, 0);
    sa1 = __builtin_amdgcn_mfma_f32_32x32x16_bf16(kc13, qf[3], sa1, 0, 0, 0);
    __builtin_amdgcn_s_setprio(0);

    // causal mask (t==qw: diagonal; t>qw: fully masked -> tile contributes nothing)
    if (t0 >= qw) {
#pragma unroll
      for (int r = 0; r < 16; ++r) {
        int kv_g = t0 * 32 + (r & 3) + 8 * (r >> 2) + 4 * hi;
        if (kv_g > q_g) sa0[r] = -1e30f;
      }
    }
    if (t1 >= qw) {
#pragma unroll
      for (int r = 0; r < 16; ++r) {
        int kv_g = t1 * 32 + (r & 3) + 8 * (r >> 2) + 4 * hi;
        if (kv_g > q_g) sa1[r] = -1e30f;
      }
    }

    // no-max softmax, both tiles (independent chains)
    float p0[16], p1[16];
#pragma unroll
    for (int r = 0; r < 16; ++r) p0[r] = exp2f(sa0[r]);
#pragma unroll
    for (int r = 0; r < 16; ++r) p1[r] = exp2f(sa1[r]);
    {
      float s00 = (p0[0] + p0[1]) + (p0[2] + p0[3]);
      float s01 = (p0[4] + p0[5]) + (p0[6] + p0[7]);
      float s02 = (p0[8] + p0[9]) + (p0[10] + p0[11]);
      float s03 = (p0[12] + p0[13]) + (p0[14] + p0[15]);
      float s10 = (p1[0] + p1[1]) + (p1[2] + p1[3]);
      float s11 = (p1[4] + p1[5]) + (p1[6] + p1[7]);
      float s12 = (p1[8] + p1[9]) + (p1[10] + p1[11]);
      float s13 = (p1[12] + p1[13]) + (p1[14] + p1[15]);
      l += ((s00 + s01) + (s02 + s03)) + ((s10 + s11) + (s12 + s13));
    }

    // pack + PV tile 0
    {
      short8 v00 = *(const short8*)&Vs[pb][0][ln][((0 + hi) ^ (ln & 3)) * 8];
      short8 v01 = *(const short8*)&Vs[pb][0][ln][((2 + hi) ^ (ln & 3)) * 8];
      short8 v10 = *(const short8*)&Vs[pb][0][32 + ln][((0 + hi) ^ (ln & 3)) * 8];
      short8 v11 = *(const short8*)&Vs[pb][0][32 + ln][((2 + hi) ^ (ln & 3)) * 8];
#pragma unroll
      for (int s = 0; s < 2; ++s) {
        unsigned c0 = cvtpk(p0[8 * s + 0], p0[8 * s + 1]);
        unsigned c1 = cvtpk(p0[8 * s + 2], p0[8 * s + 3]);
        unsigned c2 = cvtpk(p0[8 * s + 4], p0[8 * s + 5]);
        unsigned c3 = cvtpk(p0[8 * s + 6], p0[8 * s + 7]);
        unsigned pc0 = (unsigned)__shfl_xor((int)c0, 32);
        unsigned pc1 = (unsigned)__shfl_xor((int)c1, 32);
        unsigned pc2 = (unsigned)__shfl_xor((int)c2, 32);
        unsigned pc3 = (unsigned)__shfl_xor((int)c3, 32);
        union { unsigned u[4]; short8 v; } pbv;
        pbv.u[0] = hi ? pc2 : c0;
        pbv.u[1] = hi ? pc3 : c1;
        pbv.u[2] = hi ? c2 : pc0;
        pbv.u[3] = hi ? c3 : pc1;
        __builtin_amdgcn_s_setprio(1);
        if (s == 0) {
          acoA = __builtin_amdgcn_mfma_f32_32x32x16_bf16(v00, pbv.v, acoA, 0, 0, 0);
          acoB = __builtin_amdgcn_mfma_f32_32x32x16_bf16(v10, pbv.v, acoB, 0, 0, 0);
        } else {
          acoA = __builtin_amdgcn_mfma_f32_32x32x16_bf16(v01, pbv.v, acoA, 0, 0, 0);
          acoB = __builtin_amdgcn_mfma_f32_32x32x16_bf16(v11, pbv.v, acoB, 0, 0, 0);
        }
        __builtin_amdgcn_s_setprio(0);
      }
    }
    // pack + PV tile 1
    {
      short8 v00 = *(const short8*)&Vs[pb][1][ln][((0 + hi) ^ (ln & 3)) * 8];
      short8 v01 = *(const short8*)&Vs[pb][1][ln][((2 + hi) ^ (ln & 3)) * 8];
      short8 v10 = *(const short8*)&Vs[pb][1][32 + ln][((0 + hi) ^ (ln & 3)) * 8];
      short8 v11 = *(const short8*)&Vs[pb][1][32 + ln][((2 + hi) ^ (ln & 3)) * 8];
#pragma unroll
      for (int s = 0; s < 2; ++s) {
        unsigned c0 = cvtpk(p1[8 * s + 0], p1[8 * s + 1]);
        unsigned c1 = cvtpk(p1[8 * s + 2], p1[8 * s + 3]);
        unsigned c2 = cvtpk(p1[8 * s + 4], p1[8 * s + 5]);
        unsigned c3 = cvtpk(p1[8 * s + 6], p1[8 * s + 7]);
        unsigned pc0 = (unsigned)__shfl_xor((int)c0, 32);
        unsigned pc1 = (unsigned)__shfl_xor((int)c1, 32);
        unsigned pc2 = (unsigned)__shfl_xor((int)c2, 32);
        unsigned pc3 = (unsigned)__shfl_xor((int)c3, 32);
        union { unsigned u[4]; short8 v; } pbv;
        pbv.u[0] = hi ? pc2 : c0;
        pbv.u[1] = hi ? pc3 : c1;
        pbv.u[2] = hi ? c2 : pc0;
        pbv.u[3] = hi ? c3 : pc1;
        __builtin_amdgcn_s_setprio(1);
        if (s == 0) {
          acoA = __builtin_amdgcn_mfma_f32_32x32x16_bf16(v00, pbv.v, acoA, 0, 0, 0);
          acoB = __builtin_amdgcn_mfma_f32_32x32x16_bf16(v10, pbv.v, acoB, 0, 0, 0);
        } else {
          acoA = __builtin_amdgcn_mfma_f32_32x32x16_bf16(v01, pbv.v, acoA, 0, 0, 0);
          acoB = __builtin_amdgcn_mfma_f32_32x32x16_bf16(v11, pbv.v, acoB, 0, 0, 0);
        }
        __builtin_amdgcn_s_setprio(0);
      }
    }
  }

  // merge the lane^32 pair's l once, normalize, store
  l += __shfl_xor(l, 32);
  float rl = 1.f / l;
  int b = bh >> 4, h = bh & 15;
  size_t obase = ((size_t)b * 2048 + q_g) * 1024 + h * 64;
#pragma unroll
  for (int g4 = 0; g4 < 4; ++g4) {
    int d0 = 8 * g4 + 4 * hi;
    *(unsigned*)&O[obase + d0]          = cvtpk(acoA[4 * g4] * rl, acoA[4 * g4 + 1] * rl);
    *(unsigned*)&O[obase + d0 + 2]      = cvtpk(acoA[4 * g4 + 2] * rl, acoA[4 * g4 + 3] * rl);
    *(unsigned*)&O[obase + 32 + d0]     = cvtpk(acoB[4 * g4] * rl, acoB[4 * g4 + 1] * rl);
    *(unsigned*)&O[obase + 32 + d0 + 2] = cvtpk(acoB[4 * g4 + 2] * rl, acoB[4 * g4 + 3] * rl);
  }
}

extern "C" void kernel_launch(void* const* d_in, const int* in_sizes, int n_in,
                              void* d_out, int out_size, void* d_ws, size_t ws_size,
                              hipStream_t stream) {
  const float* x  = (const float*)d_in[0];
  const float* wq = (const float*)d_in[1];
  const float* wk = (const float*)d_in[2];
  const float* wv = (const float*)d_in[3];
  const float* wo = (const float*)d_in[4];
  float* out = (float*)d_out;
  char* ws = (char*)d_ws;

  short* x_bf  = (short*)(ws);                       // 8 MB
  short* WqkvT = (short*)(ws + ((size_t)8 << 20));   // 6 MB
  short* wo_bf = (short*)(ws + ((size_t)14 << 20));  // 2 MB
  short* Qb    = (short*)(ws + ((size_t)16 << 20));  // 8 MB
  short* Kb    = (short*)(ws + ((size_t)24 << 20));  // 8 MB
  short* Vt    = (short*)(ws + ((size_t)32 << 20));  // 8 MB (V^T)
  short* Ob    = (short*)(ws + ((size_t)40 << 20));  // 8 MB

  k_cast<<<4096, 256, 0, stream>>>(x, x_bf, 1048576);
  k_cast<<<1024, 256, 0, stream>>>(wo, wo_bf, 262144);
  k_pack<<<dim3(16, 16, 3), 256, 0, stream>>>(wq, wk, wv, WqkvT);
  k_gemm<0><<<dim3(24, 32), 256, 0, stream>>>(x_bf, WqkvT, Qb, Kb, Vt, nullptr, 4096, 3072, 1024);
  k_attn<<<dim3(32, 32), 128, 0, stream>>>(Qb, Kb, Vt, Ob);
  k_gemm<1><<<dim3(8, 32), 256, 0, stream>>>(Ob, wo_bf, nullptr, nullptr, nullptr, out, 4096, 1024, 1024);
}